// Round 3
// baseline (268.047 us; speedup 1.0000x reference)
//
#include <hip/hip_runtime.h>

// ParabolicUnpool2D, B=16 C=64 HP=WP=112 STRIDE=2 KS=3, HO=WO=224.
// Closed form (t>=0 => kern center 0 >= edge -t/2 >= corner -t):
//   out[2i,2j]     = max(x[i,j], -t/2)
//   out[2i,2j+1]   = max(0, max(x[i,j],   x[i,j+1]) - t/2)
//   out[2i+1,2j]   = max(0, max(x[i,j],   x[i+1,j]) - t/2)
//   out[2i+1,2j+1] = max(0, max(x[i,j], x[i,j+1], x[i+1,j], x[i+1,j+1]) - t)
// Out-of-range x treated as -1e30 (reference NEG_INF padding).
// indices input (d_in[2]) is deterministic -> never read.

#define HP 112
#define WP 112
#define HO 224
#define WO 224
#define NEGBIG (-1e30f)

// Native clang vector type: __builtin_nontemporal_store rejects HIP's
// float4 class but accepts ext_vector_type.
typedef float vfloat4 __attribute__((ext_vector_type(4)));

// Each thread handles one (bc, i, k) where k covers input cols j0=2k, 2k+1.
// Writes two float4 (output rows 2i and 2i+1, cols 4k..4k+3) as nontemporal
// streaming stores (output is write-once, never re-read -> don't thrash L2;
// x rows ARE re-read by the thread-row above, keep those cached).
__global__ __launch_bounds__(256) void parabolic_unpool_kernel(
    const float* __restrict__ x, const float* __restrict__ t,
    float* __restrict__ out, int total) {
  int idx = blockIdx.x * blockDim.x + threadIdx.x;
  const int stride = gridDim.x * blockDim.x;
  for (; idx < total; idx += stride) {
    const int k  = idx % 56;          // input col pair: j0 = 2k
    const int r  = idx / 56;
    const int i  = r % HP;            // input row
    const int bc = r / HP;            // b*64 + c
    const int c  = bc & 63;

    const float tv = t[c];
    const float th = -0.5f * tv;      // edge kern
    const float tc = -tv;             // corner kern

    const int j0 = 2 * k;
    const float* xrow = x + ((size_t)bc * HP + i) * WP;

    const float2 a = *(const float2*)(xrow + j0);     // x[i,j0], x[i,j0+1]
    const float a2 = (j0 + 2 < WP) ? xrow[j0 + 2] : NEGBIG;

    float b0, b1, b2;
    if (i + 1 < HP) {
      const float* xrow1 = xrow + WP;
      const float2 bv = *(const float2*)(xrow1 + j0);
      b0 = bv.x; b1 = bv.y;
      b2 = (j0 + 2 < WP) ? xrow1[j0 + 2] : NEGBIG;
    } else {
      b0 = NEGBIG; b1 = NEGBIG; b2 = NEGBIG;
    }

    // Even output row (2i), cols 4k..4k+3
    vfloat4 e;
    e.x = fmaxf(a.x, th);
    e.y = fmaxf(0.0f, fmaxf(a.x, a.y) + th);
    e.z = fmaxf(a.y, th);
    e.w = fmaxf(0.0f, fmaxf(a.y, a2) + th);

    // Odd output row (2i+1)
    vfloat4 o;
    o.x = fmaxf(0.0f, fmaxf(a.x, b0) + th);
    o.y = fmaxf(0.0f, fmaxf(fmaxf(a.x, a.y), fmaxf(b0, b1)) + tc);
    o.z = fmaxf(0.0f, fmaxf(a.y, b1) + th);
    o.w = fmaxf(0.0f, fmaxf(fmaxf(a.y, a2), fmaxf(b1, b2)) + tc);

    float* orow = out + ((size_t)bc * HO + 2 * i) * WO + 4 * k;
    __builtin_nontemporal_store(e, (vfloat4*)orow);
    __builtin_nontemporal_store(o, (vfloat4*)(orow + WO));
  }
}

extern "C" void kernel_launch(void* const* d_in, const int* in_sizes, int n_in,
                              void* d_out, int out_size, void* d_ws, size_t ws_size,
                              hipStream_t stream) {
  const float* x = (const float*)d_in[0];
  const float* t = (const float*)d_in[1];
  // d_in[2] (indices) intentionally unused: deterministic stride-2 layout.
  float* out = (float*)d_out;

  const int total = 16 * 64 * HP * (WP / 2);  // 6,422,528 work items
  const int block = 256;
  const int maxBlocks = 2048;                 // grid-stride, ~8 blocks/CU
  int blocks = (total + block - 1) / block;
  if (blocks > maxBlocks) blocks = maxBlocks;

  parabolic_unpool_kernel<<<blocks, block, 0, stream>>>(x, t, out, total);
}

// Round 4
// 261.024 us; speedup vs baseline: 1.0269x; 1.0269x over previous
//
#include <hip/hip_runtime.h>

// ParabolicUnpool2D, B=16 C=64 HP=WP=112 STRIDE=2 KS=3, HO=WO=224.
// Closed form (t>=0 => kern center 0 >= edge -t/2 >= corner -t):
//   out[2i,2j]     = max(x[i,j], -t/2)
//   out[2i,2j+1]   = max(0, max(x[i,j],   x[i,j+1]) - t/2)
//   out[2i+1,2j]   = max(0, max(x[i,j],   x[i+1,j]) - t/2)
//   out[2i+1,2j+1] = max(0, max(x[i,j], x[i,j+1], x[i+1,j], x[i+1,j+1]) - t)
// Out-of-range x treated as -1e30 (reference NEG_INF padding).
// indices input (d_in[2]) is deterministic -> never read.
//
// R3 -> R4: removed nontemporal stores (poison fill sustains 6.5 TB/s through
// the normal L2 write path; nt was the prime suspect for kernel ~2.7 TB/s).
// Removed grid-stride loop: exact grid, one work item per thread.

#define HP 112
#define WP 112
#define HO 224
#define WO 224
#define NEGBIG (-1e30f)

__global__ __launch_bounds__(256) void parabolic_unpool_kernel(
    const float* __restrict__ x, const float* __restrict__ t,
    float* __restrict__ out) {
  const int idx = blockIdx.x * 256 + threadIdx.x;   // exact grid, no tail

  const int k  = idx % 56;          // input col pair: j0 = 2k
  const int r  = idx / 56;
  const int i  = r % HP;            // input row
  const int bc = r / HP;            // b*64 + c
  const int c  = bc & 63;

  const float tv = t[c];
  const float th = -0.5f * tv;      // edge kern
  const float tc = -tv;             // corner kern

  const int j0 = 2 * k;
  const float* xrow = x + ((size_t)bc * HP + i) * WP;

  const float2 a = *(const float2*)(xrow + j0);     // x[i,j0], x[i,j0+1]
  const float a2 = (j0 + 2 < WP) ? xrow[j0 + 2] : NEGBIG;

  float b0, b1, b2;
  if (i + 1 < HP) {
    const float* xrow1 = xrow + WP;
    const float2 bv = *(const float2*)(xrow1 + j0);
    b0 = bv.x; b1 = bv.y;
    b2 = (j0 + 2 < WP) ? xrow1[j0 + 2] : NEGBIG;
  } else {
    b0 = NEGBIG; b1 = NEGBIG; b2 = NEGBIG;
  }

  // Even output row (2i), cols 4k..4k+3
  float4 e;
  e.x = fmaxf(a.x, th);
  e.y = fmaxf(0.0f, fmaxf(a.x, a.y) + th);
  e.z = fmaxf(a.y, th);
  e.w = fmaxf(0.0f, fmaxf(a.y, a2) + th);

  // Odd output row (2i+1)
  float4 o;
  o.x = fmaxf(0.0f, fmaxf(a.x, b0) + th);
  o.y = fmaxf(0.0f, fmaxf(fmaxf(a.x, a.y), fmaxf(b0, b1)) + tc);
  o.z = fmaxf(0.0f, fmaxf(a.y, b1) + th);
  o.w = fmaxf(0.0f, fmaxf(fmaxf(a.y, a2), fmaxf(b1, b2)) + tc);

  float* orow = out + ((size_t)bc * HO + 2 * i) * WO + 4 * k;
  *(float4*)orow = e;
  *(float4*)(orow + WO) = o;
}

extern "C" void kernel_launch(void* const* d_in, const int* in_sizes, int n_in,
                              void* d_out, int out_size, void* d_ws, size_t ws_size,
                              hipStream_t stream) {
  const float* x = (const float*)d_in[0];
  const float* t = (const float*)d_in[1];
  // d_in[2] (indices) intentionally unused: deterministic stride-2 layout.
  float* out = (float*)d_out;

  const int total = 16 * 64 * HP * (WP / 2);  // 6,422,528 work items
  const int block = 256;
  const int blocks = total / block;           // 25088, exact (no tail)

  parabolic_unpool_kernel<<<blocks, block, 0, stream>>>(x, t, out);
}